// Round 3
// baseline (172.321 us; speedup 1.0000x reference)
//
#include <hip/hip_runtime.h>

#define THREADS 256
#define BLOCKS_PER_XCD 196
#define NXCD 8
#define NBLOCKS (BLOCKS_PER_XCD * NXCD)   // 1568

typedef int   intx4   __attribute__((ext_vector_type(4)));
typedef float floatx4 __attribute__((ext_vector_type(4)));

// B=64, P=50000, H=W=512.  One thread = one unit of 8 points.
// Units per batch = 50000/8 = 6250; units per XCD = 8 batches * 6250 = 50000.
// Threads per XCD = 196*256 = 50176 (176 idle; no loop, no tail).
__global__ __launch_bounds__(THREADS) void rdc_kernel(
    const float* __restrict__ x,
    const int*   __restrict__ xA,
    const int*   __restrict__ yA,
    const int*   __restrict__ xB,
    const int*   __restrict__ yB,
    const float* __restrict__ gt,
    float* __restrict__ out,
    float inv_n)
{
    const int UPB = 6250;             // units per batch
    const int HW  = 512 * 512;

    // Physical mapping: consecutive block ids round-robin across the 8 XCDs.
    const int xcd = blockIdx.x & 7;
    const int lb  = blockIdx.x >> 3;                 // 0..195
    const int tlocal = lb * THREADS + threadIdx.x;   // 0..50175

    float acc = 0.0f;
    if (tlocal < 8 * UPB) {
        const int bl = tlocal / UPB;                 // local batch 0..7
        const int i  = tlocal - bl * UPB;            // unit within batch
        const int b  = xcd * 8 + bl;                 // global batch
        const int v2 = (b * UPB + i) * 2;            // vec4 chunk base (2 per unit)

        // Read-once streams: nontemporal, 10 independent 16B loads.
        const intx4  xa0 = __builtin_nontemporal_load((const intx4*)xA + v2);
        const intx4  xa1 = __builtin_nontemporal_load((const intx4*)xA + v2 + 1);
        const intx4  ya0 = __builtin_nontemporal_load((const intx4*)yA + v2);
        const intx4  ya1 = __builtin_nontemporal_load((const intx4*)yA + v2 + 1);
        const intx4  xb0 = __builtin_nontemporal_load((const intx4*)xB + v2);
        const intx4  xb1 = __builtin_nontemporal_load((const intx4*)xB + v2 + 1);
        const intx4  yb0 = __builtin_nontemporal_load((const intx4*)yB + v2);
        const intx4  yb1 = __builtin_nontemporal_load((const intx4*)yB + v2 + 1);
        const floatx4 g0 = __builtin_nontemporal_load((const floatx4*)gt + v2);
        const floatx4 g1 = __builtin_nontemporal_load((const floatx4*)gt + v2 + 1);

        const float* __restrict__ img = x + (size_t)b * HW;

        // Issue all 16 gathers before any use: compute z values first.
        float zA[8], zB[8];
        #pragma unroll
        for (int k = 0; k < 4; ++k) {
            zA[k]     = img[(ya0[k] << 9) + xa0[k]];
            zA[k + 4] = img[(ya1[k] << 9) + xa1[k]];
            zB[k]     = img[(yb0[k] << 9) + xb0[k]];
            zB[k + 4] = img[(yb1[k] << 9) + xb1[k]];
        }

        #pragma unroll
        for (int k = 0; k < 8; ++k) {
            float gi = (k < 4) ? g0[k] : g1[k - 4];
            float d  = zA[k] - zB[k];
            float t  = -gi * d;
            // stable softplus: log1p(exp(t)) = max(t,0) + log1p(exp(-|t|))
            float sp = fmaxf(t, 0.0f) + log1pf(__expf(-fabsf(t)));
            float m  = fabsf(gi);     // 0 or 1
            acc += m * sp + (1.0f - m) * d * d;
        }
    }

    // wave64 reduce
    #pragma unroll
    for (int off = 32; off > 0; off >>= 1)
        acc += __shfl_down(acc, off, 64);

    __shared__ float wsum[THREADS / 64];
    const int lane = threadIdx.x & 63;
    const int wid  = threadIdx.x >> 6;
    if (lane == 0) wsum[wid] = acc;
    __syncthreads();
    if (threadIdx.x == 0) {
        float s = 0.0f;
        #pragma unroll
        for (int i2 = 0; i2 < THREADS / 64; ++i2) s += wsum[i2];
        atomicAdd(out, s * inv_n);
    }
}

extern "C" void kernel_launch(void* const* d_in, const int* in_sizes, int n_in,
                              void* d_out, int out_size, void* d_ws, size_t ws_size,
                              hipStream_t stream) {
    const float* x  = (const float*)d_in[0];
    const int*   xA = (const int*)d_in[1];
    const int*   yA = (const int*)d_in[2];
    const int*   xB = (const int*)d_in[3];
    const int*   yB = (const int*)d_in[4];
    const float* gt = (const float*)d_in[5];
    float* out = (float*)d_out;

    const int n = in_sizes[1];             // B*P = 3,200,000
    const float inv_n = 1.0f / (float)n;

    hipMemsetAsync(out, 0, sizeof(float), stream);
    rdc_kernel<<<NBLOCKS, THREADS, 0, stream>>>(x, xA, yA, xB, yB, gt, out, inv_n);
}